// Round 9
// baseline (583.748 us; speedup 1.0000x reference)
//
#include <hip/hip_runtime.h>
#include <cstdint>
#include <cstddef>

#define H_ 64
#define W_ 64
#define T_ 32
#define CIN_ 16
#define COUT_ 64
#define TH_ 4
#define TW_ 16
#define NROW_ 6
#define NCOL_ 18
#define NPOS_ (NROW_ * NCOL_)     // 108
#define XEL_ (NPOS_ * CIN_)       // 1728 elems per slice
#define SLOT_DW_ (NPOS_ * 20)     // 2160 dwords per slot (16 data + 4 pad per pos)
#define NTHR_ 1024

// ---- prep: w2[g=cout>>2][cinq][r=dz*9+dy*3+dx][ci4][co4], Gram d64, inv64 ----
__global__ void prep(const float* __restrict__ w, float* __restrict__ w2,
                     double* __restrict__ d64, double* __restrict__ inv64) {
    const int i = blockIdx.x;   // cout 0..63
    const int j = threadIdx.x;  // 0..63
    const float* wi = w + i * 432;
    const float* wj = w + j * 432;
    double acc = 0.0;
    for (int k = 0; k < 432; ++k) acc += (double)wi[k] * (double)wj[k];
    d64[i * 64 + j] = acc;
    if (i == j) inv64[i] = 1.0 / (acc + 1e-8);
    for (int k = j; k < 432; k += 64) {
        const int cin = k / 27, r = k - cin * 27;
        const int off = ((((i >> 2) * 4 + (cin >> 2)) * 27 + r) * 4 + (cin & 3)) * 4 + (i & 3);
        w2[off] = wi[k];
    }
}

// ---- fused conv3d + spiking recurrence (cin-quad b128 x-reads) ----
__launch_bounds__(NTHR_, 1)
__global__ void fused_snn(const float* __restrict__ xg,
                          const float* __restrict__ beta_g, const float* __restrict__ bias_g,
                          const float* __restrict__ w2, const double* __restrict__ d64,
                          const double* __restrict__ inv64, float* __restrict__ out) {
    __shared__ __align__(16) float4 xQ[4][NPOS_][5];        // 34560 B, slot = z&3
    __shared__ __align__(16) double d_lds[64 * 65];         // 33280 B (padded rows)
    __shared__ unsigned int masks[2][64][2];                // 1024 B

    const int tid = threadIdx.x;
    const int b   = blockIdx.x;          // batch 0..3
    const int ty0 = blockIdx.y * TH_;
    const int tx0 = blockIdx.z * TW_;

    const int wv   = __builtin_amdgcn_readfirstlane(tid >> 6);  // wave 0..15
    const int lane = tid & 63;
    const int py   = lane >> 4;          // 0..3
    const int px   = lane & 15;          // 0..15
    const int c0   = wv * 4;             // wave owns couts [c0, c0+4)

    const float* wbase = w2 + (size_t)wv * 1728;   // wave's contiguous weights (6912 B)
    float* xF = (float*)&xQ[0][0][0];

    for (int i = tid; i < 4096; i += NTHR_)
        d_lds[(i >> 6) * 65 + (i & 63)] = d64[i];
    if (tid < 128) masks[1][tid >> 1][tid & 1] = 0u;  // rbuf for t=0

    // stage slices z=0,1 into slots 0,1
    for (int z = 0; z < 2; ++z) {
        for (int i = tid; i < XEL_; i += NTHR_) {
            const int pos = i >> 4, cin = i & 15;
            const int yy = pos / NCOL_, xx = pos - yy * NCOL_;
            const int gy = ty0 - 1 + yy, gx = tx0 - 1 + xx;
            float v = 0.f;
            if (gy >= 0 && gy < H_ && gx >= 0 && gx < W_)
                v = xg[((size_t)(b * CIN_ + cin) * T_ + z) * (H_ * W_) + gy * W_ + gx];
            xF[z * SLOT_DW_ + pos * 20 + cin] = v;
        }
    }

    const double beta = (double)beta_g[0];
    const double omb  = 1.0 - beta;
    double inv_[4], bb[4];
#pragma unroll
    for (int ci = 0; ci < 4; ++ci) {
        inv_[ci] = inv64[c0 + ci];
        bb[ci]   = (double)bias_g[c0 + ci];
    }
    double mem[4];
#pragma unroll
    for (int ci = 0; ci < 4; ++ci) mem[ci] = 0.0;

    // prefetch/staging index precompute (2 elems per thread: 1728/1024)
    int  pf_ldw[2];
    size_t pf_goff[2];
    bool pf_ok[2], pf_in[2];
#pragma unroll
    for (int r = 0; r < 2; ++r) {
        const int i = tid + r * NTHR_;
        pf_ok[r] = (i < XEL_);
        const int pos = (i >> 4) % NPOS_, cin = i & 15;
        const int yy = pos / NCOL_, xx = pos - yy * NCOL_;
        const int gy = ty0 - 1 + yy, gx = tx0 - 1 + xx;
        pf_ldw[r] = pos * 20 + cin;
        pf_in[r]  = pf_ok[r] && gy >= 0 && gy < H_ && gx >= 0 && gx < W_;
        pf_goff[r] = (size_t)(b * CIN_ + cin) * (T_ * H_ * W_) + (size_t)gy * W_ + gx;
    }

    for (int t = 0; t < T_; ++t) {
        __syncthreads();   // A: prev staging writes + prev mask ORs visible
        if (tid < 128) masks[t & 1][tid >> 1][tid & 1] = 0u;  // clear wbuf

        // prefetch slice z=t+2 into regs (hidden under conv)
        float R[2];
        const int zp = t + 2;
        if (zp < T_) {
#pragma unroll
            for (int r = 0; r < 2; ++r) {
                R[r] = 0.f;
                if (pf_in[r]) R[r] = xg[pf_goff[r] + (size_t)zp * (H_ * W_)];
            }
        }

        // ---- conv: 108 ds_read_b128 per wave; fp32 products, fp64 fold per (cinq,dz) ----
        double accd[4];
#pragma unroll
        for (int ci = 0; ci < 4; ++ci) accd[ci] = 0.0;

        int slot_[3]; bool zok[3];
#pragma unroll
        for (int dz = 0; dz < 3; ++dz) {
            const int z = t - 1 + dz;
            zok[dz]  = (z >= 0 && z < T_);
            slot_[dz] = zok[dz] ? (z & 3) : 0;
        }

#pragma unroll 1
        for (int cinq = 0; cinq < 4; ++cinq) {
#pragma unroll
            for (int dz = 0; dz < 3; ++dz) {
                if (!zok[dz]) continue;
                const float4* xb = &xQ[slot_[dz]][0][0];
                const float* wp = wbase + (cinq * 27 + dz * 9) * 16;
                float cacc[4] = {0.f, 0.f, 0.f, 0.f};
#pragma unroll
                for (int dy = 0; dy < 3; ++dy) {
                    const int rb0 = (py + dy) * NCOL_ + px;
                    const float4 x0 = xb[(rb0 + 0) * 5 + cinq];
                    const float4 x1 = xb[(rb0 + 1) * 5 + cinq];
                    const float4 x2 = xb[(rb0 + 2) * 5 + cinq];
                    const float* wd = wp + dy * 48;
#pragma unroll
                    for (int co = 0; co < 4; ++co) {
                        float cc = cacc[co];
                        cc = fmaf(wd[ 0 + co], x0.x, cc);
                        cc = fmaf(wd[ 4 + co], x0.y, cc);
                        cc = fmaf(wd[ 8 + co], x0.z, cc);
                        cc = fmaf(wd[12 + co], x0.w, cc);
                        cc = fmaf(wd[16 + co], x1.x, cc);
                        cc = fmaf(wd[20 + co], x1.y, cc);
                        cc = fmaf(wd[24 + co], x1.z, cc);
                        cc = fmaf(wd[28 + co], x1.w, cc);
                        cc = fmaf(wd[32 + co], x2.x, cc);
                        cc = fmaf(wd[36 + co], x2.y, cc);
                        cc = fmaf(wd[40 + co], x2.z, cc);
                        cc = fmaf(wd[44 + co], x2.w, cc);
                        cacc[co] = cc;
                    }
                }
#pragma unroll
                for (int ci = 0; ci < 4; ++ci) accd[ci] += (double)cacc[ci];
            }
        }

        // ---- rst from previous spikes (sparse via bitmask), fp64 d ----
        double rstv[4];
#pragma unroll
        for (int ci = 0; ci < 4; ++ci) rstv[ci] = 0.0;
        const int rbuf = (t + 1) & 1;
#pragma unroll
        for (int wrd = 0; wrd < 2; ++wrd) {
            unsigned int m = masks[rbuf][lane][wrd];
            while (m) {
                const int bit = __ffs(m) - 1;
                m &= m - 1;
                const double* drow = &d_lds[(wrd * 32 + bit) * 65 + c0];
#pragma unroll
                for (int ci = 0; ci < 4; ++ci) rstv[ci] += drow[ci];
            }
        }

        // ---- membrane update, spike, store ----
        unsigned int nib = 0u;
        const size_t obase = ((size_t)(b * COUT_ + c0) * T_ + t) * (size_t)(H_ * W_)
                           + (size_t)(ty0 + py) * W_ + (tx0 + px);
#pragma unroll
        for (int ci = 0; ci < 4; ++ci) {
            mem[ci] = (mem[ci] - rstv[ci]) * beta + accd[ci] * omb;
            const double mthr = mem[ci] * inv_[ci] - bb[ci];
            const int s = mthr > 0.0 ? 1 : 0;
            out[obase + (size_t)ci * (T_ * H_ * W_)] = (float)s;
            nib |= (unsigned int)s << ci;
        }

        __syncthreads();   // B: clears + conv reads done before ORs / staging writes
        if (nib) atomicOr(&masks[t & 1][lane][wv >> 3], nib << ((wv & 7) * 4));

        // write prefetched slice z=t+2 into slot (t+2)&3 (not read this iter)
        if (zp < T_) {
            const int so = (zp & 3) * SLOT_DW_;
#pragma unroll
            for (int r = 0; r < 2; ++r)
                if (pf_ok[r]) xF[so + pf_ldw[r]] = R[r];
        }
    }
}

extern "C" void kernel_launch(void* const* d_in, const int* in_sizes, int n_in,
                              void* d_out, int out_size, void* d_ws, size_t ws_size,
                              hipStream_t stream) {
    const float* x    = (const float*)d_in[0];
    const float* w    = (const float*)d_in[1];
    const float* beta = (const float*)d_in[2];
    const float* bias = (const float*)d_in[3];
    float* out = (float*)d_out;

    float*  w2    = (float*)d_ws;                                   // 110592 B
    double* d64   = (double*)((char*)d_ws + 110592);                // 32768 B
    double* inv64 = (double*)((char*)d_ws + 110592 + 32768);        // 512 B

    prep<<<dim3(64), dim3(64), 0, stream>>>(w, w2, d64, inv64);
    fused_snn<<<dim3(4, 16, 4), dim3(NTHR_), 0, stream>>>(x, beta, bias, w2, d64, inv64, out);
}